// Round 6
// baseline (42718.851 us; speedup 1.0000x reference)
//
#include <hip/hip_runtime.h>

// 2-layer GRU, I=8, H=128, T=32768 sequential steps, out = final h1 (128 f32).
// ZERO inter-block sync design: three kernels, sequential on one stream
// (kernel boundary = ordering + visibility; no flags, no spins, no deadlock):
//   1) gru_layer0 : 1 block, full layer-0 recurrence, writes h0[T] to ws
//   2) gru_gi1    : throughput grid, gi1[t] = w_ih1 @ h0[t] + b_ih1 (all t)
//   3) gru_layer1 : 1 block, layer-1 recurrence consuming gi1 stream
// Recurrence weights are pinned in VGPRs via inline-asm loads (cannot be
// rematerialized -> true residency; r1 counters proved compiler re-streams
// weights from L2 every step otherwise: FETCH 36.7GB = 6blk*32768*192KB).
// gi1 is chunked if ws is small (h0 16MB always resident in ws).

#define T_STEPS 32768
#define HDIM 128
#define GS 8

typedef __attribute__((ext_vector_type(2))) float f32x2;
typedef __attribute__((ext_vector_type(4))) float f32x4;

__device__ __forceinline__ f32x2 lo2(f32x4 v) { return __builtin_shufflevector(v, v, 0, 1); }
__device__ __forceinline__ f32x2 hi2(f32x4 v) { return __builtin_shufflevector(v, v, 2, 3); }
__device__ __forceinline__ void pkfma(f32x2& acc, f32x2 a, f32x2 b) {
  asm("v_pk_fma_f32 %0, %1, %2, %0" : "+v"(acc) : "v"(a), "v"(b));
}
__device__ __forceinline__ float sigm(float x) {
  return __fdividef(1.f, 1.f + __expf(-x));
}
__device__ __forceinline__ float tanh_fast(float x) {
  x = fminf(15.f, fmaxf(-15.f, x));
  float e = __expf(2.f * x);
  return (e - 1.f) * __fdividef(1.f, e + 1.f);
}
// quad butterfly reduce via DPP quad_perm — numerically == shfl_xor(1);shfl_xor(2)
__device__ __forceinline__ float red4q(float v) {
  int t = __builtin_amdgcn_mov_dpp(__builtin_bit_cast(int, v), 0xB1, 0xF, 0xF, true);
  v += __builtin_bit_cast(float, t);
  t = __builtin_amdgcn_mov_dpp(__builtin_bit_cast(int, v), 0x4E, 0xF, 0xF, true);
  v += __builtin_bit_cast(float, t);
  return v;
}
// Pinned loads: asm results cannot be rematerialized -> stay in VGPRs.
// (vmcnt safety: HW retires VMEM in issue order, so compiler-inserted
// s_waitcnt vmcnt(N) for its own younger loads remains conservative.)
__device__ __forceinline__ f32x4 ld4_pin(const float* p) {
  f32x4 v;
  asm volatile("global_load_dwordx4 %0, %1, off" : "=v"(v) : "v"(p));
  return v;
}
__device__ __forceinline__ float ld1_pin(const float* p) {
  float v;
  asm volatile("global_load_dword %0, %1, off" : "=v"(v) : "v"(p));
  return v;
}
__device__ __forceinline__ void vwait() {
  asm volatile("s_waitcnt vmcnt(0)" ::: "memory");
}

// Thread t: q=t&3 (32-float h chunk), u=t>>2 (hidden unit; rows u,u+128,u+256).
// Weights PRE-ROTATED: slot r holds source vector k=r^2q -> the 4 q-groups read
// 4 disjoint 16B quads of hbuf per slot (broadcast within group, conflict-free),
// and all weight indices stay compile-time constants.
__device__ __forceinline__ void load_w3_pin(const float* __restrict__ W, int u, int q,
                                            f32x4 (&w0)[8], f32x4 (&w1)[8], f32x4 (&w2)[8]) {
  #pragma unroll
  for (int r = 0; r < 8; ++r) {
    const int k = r ^ (q << 1);
    const int col = 32 * q + 4 * k;
    w0[r] = ld4_pin(W + (size_t)u * 128 + col);
    w1[r] = ld4_pin(W + (size_t)(u + 128) * 128 + col);
    w2[r] = ld4_pin(W + (size_t)(u + 256) * 128 + col);
  }
}

// r1/r2-proven dot association: pkfma pairs, rotated order, quad reduce
__device__ __forceinline__ void dot3_pk(const f32x4 (&w0)[8], const f32x4 (&w1)[8],
                                        const f32x4 (&w2)[8], const float* hb, int q,
                                        float& a0, float& a1, float& a2) {
  f32x2 c0 = {0.f, 0.f}, c1 = {0.f, 0.f}, c2 = {0.f, 0.f};
  const int base = 32 * q;
  #pragma unroll
  for (int r = 0; r < 8; ++r) {
    const int k = r ^ (q << 1);
    f32x4 h4 = *(const f32x4*)(hb + base + 4 * k);
    f32x2 hl = lo2(h4), hh = hi2(h4);
    pkfma(c0, lo2(w0[r]), hl); pkfma(c0, hi2(w0[r]), hh);
    pkfma(c1, lo2(w1[r]), hl); pkfma(c1, hi2(w1[r]), hh);
    pkfma(c2, lo2(w2[r]), hl); pkfma(c2, hi2(w2[r]), hh);
  }
  a0 = red4q(c0.x + c0.y);
  a1 = red4q(c1.x + c1.y);
  a2 = red4q(c2.x + c2.y);
}

// r1-exact x-dot association: bias-seeded sequential fmaf over i=0..7
__device__ __forceinline__ float dot8_seq(float acc, f32x4 wa, f32x4 wb,
                                          f32x4 xa, f32x4 xb) {
  acc = fmaf(wa.x, xa.x, acc); acc = fmaf(wa.y, xa.y, acc);
  acc = fmaf(wa.z, xa.z, acc); acc = fmaf(wa.w, xa.w, acc);
  acc = fmaf(wb.x, xb.x, acc); acc = fmaf(wb.y, xb.y, acc);
  acc = fmaf(wb.z, xb.z, acc); acc = fmaf(wb.w, xb.w, acc);
  return acc;
}

// ===================== kernel 1: layer-0 recurrence =====================
__global__ __attribute__((amdgpu_flat_work_group_size(512, 512),
                          amdgpu_waves_per_eu(2, 2)))
void gru_layer0(const float* __restrict__ x, const float* __restrict__ w_ih0,
                const float* __restrict__ w_hh0, const float* __restrict__ b_ih0,
                const float* __restrict__ b_hh0, float* __restrict__ h0_out) {
  __shared__ __align__(16) float hbuf[2][HDIM];
  __shared__ __align__(16) float xsg[2][GS * 8];   // x group staging (64 f32 each)
  const int tid = threadIdx.x, q = tid & 3, u = tid >> 2;
  if (tid < 2 * HDIM) ((float*)hbuf)[tid] = 0.f;

  f32x4 w0[8], w1[8], w2[8];
  load_w3_pin(w_hh0, u, q, w0, w1, w2);
  f32x4 wiA[3], wiB[3];
  #pragma unroll
  for (int m = 0; m < 3; ++m) {
    wiA[m] = ld4_pin(w_ih0 + (size_t)(u + 128 * m) * 8);
    wiB[m] = ld4_pin(w_ih0 + (size_t)(u + 128 * m) * 8 + 4);
  }
  const float bi_r = ld1_pin(b_ih0 + u), bh_r = ld1_pin(b_hh0 + u);
  const float bi_z = ld1_pin(b_ih0 + u + 128), bh_z = ld1_pin(b_hh0 + u + 128);
  const float bi_n = ld1_pin(b_ih0 + u + 256), bh_n = ld1_pin(b_hh0 + u + 256);
  vwait();
  const float bsr = bi_r + bh_r, bsz = bi_z + bh_z, bin = bi_n, bhn = bh_n;

  if (tid < 16) *(f32x4*)&xsg[0][tid * 4] = *(const f32x4*)(x + tid * 4);
  __syncthreads();

  int cur = 0;
  const int NG = T_STEPS / GS;
  for (int g = 0; g < NG; ++g) {
    f32x4 pf;
    const bool hp_ = (g + 1 < NG) && (tid < 16);
    if (hp_) pf = *(const f32x4*)(x + (size_t)(g + 1) * (GS * 8) + tid * 4);
    #pragma unroll
    for (int s = 0; s < GS; ++s) {
      const int pr = s & 1;
      float a0, a1, a2;
      dot3_pk(w0, w1, w2, hbuf[pr], q, a0, a1, a2);
      if (s == GS - 1 && hp_) *(f32x4*)&xsg[cur ^ 1][tid * 4] = pf;
      if (q == 0) {
        const f32x4 xlo = *(const f32x4*)&xsg[cur][s * 8];
        const f32x4 xhi = *(const f32x4*)&xsg[cur][s * 8 + 4];
        const float gr = dot8_seq(bsr, wiA[0], wiB[0], xlo, xhi);
        const float gz = dot8_seq(bsz, wiA[1], wiB[1], xlo, xhi);
        const float gn = dot8_seq(bin, wiA[2], wiB[2], xlo, xhi);
        const float r = sigm(gr + a0);
        const float z = sigm(gz + a1);
        const float n = tanh_fast(gn + r * (a2 + bhn));
        const float hp2 = hbuf[pr][u];
        const float hn_ = (1.f - z) * n + z * hp2;
        hbuf[pr ^ 1][u] = hn_;
        h0_out[(size_t)(g * GS + s) * HDIM + u] = hn_;
      }
      __syncthreads();
    }
    cur ^= 1;
  }
}

// ============ kernel 2: gi1[t] = w_ih1 @ h0[t] + b_ih1 (throughput) ============
// grid = 3*nb blocks: rb = gate-row block (0..2 -> rows rb*128+u), tb = t-chunk.
__global__ __launch_bounds__(512)
void gru_gi1(const float* __restrict__ h0, const float* __restrict__ w_ih1,
             const float* __restrict__ b_ih1, float* __restrict__ gi1,
             int c0, int nb) {
  __shared__ __align__(16) float hsg[GS * HDIM];
  const int tid = threadIdx.x, q = tid & 3, u = tid >> 2;
  const int tb = blockIdx.x % nb, rb = blockIdx.x / nb;
  const int row = rb * HDIM + u;
  f32x4 w[8];
  #pragma unroll
  for (int r = 0; r < 8; ++r)
    w[r] = *(const f32x4*)(w_ih1 + (size_t)row * 128 + 32 * q + 4 * (r ^ (q << 1)));
  const float bias = b_ih1[row];
  const int t0 = c0 + tb * 512;

  for (int gg = 0; gg < 512 / GS; ++gg) {
    __syncthreads();  // protect hsg reuse
    if (tid < 256)
      ((f32x4*)hsg)[tid] =
          ((const f32x4*)(h0 + (size_t)(t0 + gg * GS) * HDIM))[tid];
    __syncthreads();
    #pragma unroll
    for (int s = 0; s < GS; ++s) {
      f32x2 c = {0.f, 0.f};
      const float* hb = hsg + s * HDIM + 32 * q;
      #pragma unroll
      for (int r = 0; r < 8; ++r) {
        f32x4 h4 = *(const f32x4*)(hb + 4 * (r ^ (q << 1)));
        pkfma(c, lo2(w[r]), lo2(h4));
        pkfma(c, hi2(w[r]), hi2(h4));
      }
      const float a = red4q(c.x + c.y);
      if (q == 0)
        gi1[(size_t)(tb * 512 + gg * GS + s) * 512 + u * 4 + rb] = a + bias;
    }
  }
}

// ===================== kernel 3: layer-1 recurrence =====================
__global__ __attribute__((amdgpu_flat_work_group_size(512, 512),
                          amdgpu_waves_per_eu(2, 2)))
void gru_layer1(const float* __restrict__ w_hh1, const float* __restrict__ b_hh1,
                const float* __restrict__ gi1, float* __restrict__ hstate,
                float* __restrict__ out, int cs, int last) {
  __shared__ __align__(16) float hbuf[2][HDIM];
  __shared__ __align__(16) float gsg[2][GS * 512];  // 2 x 16KB gi1 staging
  const int tid = threadIdx.x, q = tid & 3, u = tid >> 2;

  f32x4 w0[8], w1[8], w2[8];
  load_w3_pin(w_hh1, u, q, w0, w1, w2);
  const float bhr_ = ld1_pin(b_hh1 + u);
  const float bhz_ = ld1_pin(b_hh1 + u + 128);
  const float bhn_ = ld1_pin(b_hh1 + u + 256);
  vwait();
  const float bhr = bhr_, bhz = bhz_, bhn = bhn_;

  if (tid < HDIM) { hbuf[0][tid] = hstate[tid]; hbuf[1][tid] = 0.f; }
  {  // preload group 0
    const f32x4* b4 = (const f32x4*)gi1;
    ((f32x4*)gsg[0])[tid] = b4[tid];
    ((f32x4*)gsg[0])[tid + 512] = b4[tid + 512];
  }
  __syncthreads();

  int cur = 0;
  const int ngl = cs / GS;
  for (int g = 0; g < ngl; ++g) {
    f32x4 pf0, pf1;
    const bool hp_ = (g + 1 < ngl);
    if (hp_) {
      const f32x4* b4 = (const f32x4*)(gi1 + (size_t)(g + 1) * GS * 512);
      pf0 = b4[tid];
      pf1 = b4[tid + 512];
    }
    #pragma unroll
    for (int s = 0; s < GS; ++s) {
      const int pr = s & 1;
      float a0, a1, a2;
      dot3_pk(w0, w1, w2, hbuf[pr], q, a0, a1, a2);
      if (s == GS - 1 && hp_) {
        ((f32x4*)gsg[cur ^ 1])[tid] = pf0;
        ((f32x4*)gsg[cur ^ 1])[tid + 512] = pf1;
      }
      if (q == 0) {
        const f32x4 gv = *(const f32x4*)&gsg[cur][s * 512 + u * 4];
        const float r = sigm(gv.x + a0 + bhr);
        const float z = sigm(gv.y + a1 + bhz);
        const float n = tanh_fast(gv.z + r * (a2 + bhn));
        const float hp2 = hbuf[pr][u];
        const float hn_ = (1.f - z) * n + z * hp2;
        hbuf[pr ^ 1][u] = hn_;
      }
      __syncthreads();
    }
    cur ^= 1;
  }
  // cs is even -> final state lives in hbuf[0]
  if (tid < HDIM) {
    hstate[tid] = hbuf[0][tid];
    if (last) out[tid] = hbuf[0][tid];
  }
}

extern "C" void kernel_launch(void* const* d_in, const int* in_sizes, int n_in,
                              void* d_out, int out_size, void* d_ws, size_t ws_size,
                              hipStream_t stream) {
  (void)in_sizes; (void)n_in; (void)out_size;
  const float* x     = (const float*)d_in[0];
  const float* w_ih0 = (const float*)d_in[1];
  const float* w_hh0 = (const float*)d_in[2];
  const float* b_ih0 = (const float*)d_in[3];
  const float* b_hh0 = (const float*)d_in[4];
  const float* w_ih1 = (const float*)d_in[5];
  const float* w_hh1 = (const float*)d_in[6];
  const float* b_ih1 = (const float*)d_in[7];
  const float* b_hh1 = (const float*)d_in[8];
  float* out = (float*)d_out;

  char* ws = (char*)d_ws;
  float* hstate = (float*)ws;                             // 512 B
  float* h0     = (float*)(ws + 512);                     // 16 MB
  const size_t fixed = 512 + (size_t)T_STEPS * HDIM * 4;
  float* gi1    = (float*)(ws + fixed);                   // chunk * 2 KB

  int chunk = T_STEPS;  // steps of gi1 buffered per pass (512 f32 per step)
  while (chunk > 512 && fixed + (size_t)chunk * 512 * 4 > ws_size) chunk >>= 1;

  hipMemsetAsync(hstate, 0, 512, stream);
  hipLaunchKernelGGL(gru_layer0, dim3(1), dim3(512), 0, stream,
                     x, w_ih0, w_hh0, b_ih0, b_hh0, h0);
  for (int c0 = 0; c0 < T_STEPS; c0 += chunk) {
    const int nb = chunk / 512;
    hipLaunchKernelGGL(gru_gi1, dim3(3 * nb), dim3(512), 0, stream,
                       h0, w_ih1, b_ih1, gi1, c0, nb);
    hipLaunchKernelGGL(gru_layer1, dim3(1), dim3(512), 0, stream,
                       w_hh1, b_hh1, gi1, hstate, out, chunk,
                       (c0 + chunk) == T_STEPS ? 1 : 0);
  }
}

// Round 7
// 23303.795 us; speedup vs baseline: 1.8331x; 1.8331x over previous
//
#include <hip/hip_runtime.h>

// 2-layer GRU, I=8, H=128, T=32768 sequential steps, out = final h1 (128 f32).
// LAUNCH-LEVEL pipeline (no flags, no spins): launch k runs, as disjoint blocks,
//   block 0   : layer-0 recurrence, chunk k        (writes h0[chunk k])
//   blocks2-4 : gi1 = w_ih1@h0 + b_ih1, chunk k-1  (reads h0, writes gi1 ring)
//   block 1   : layer-1 recurrence, chunk k-2      (reads gi1 ring, writes out)
// Stream order between launches = implicit agent-scope release/acquire ->
// guaranteed visibility, zero deadlock surface. Steady state: both recurrence
// CUs run concurrently. 34 launches of 1024-step chunks.
// Weights stay in VGPRs: asm-pinned loads + per-thread demand (~120) kept under
// the RA's demonstrated allocation (r2: 128 @ __launch_bounds__(512,2)).

#define T_STEPS 32768
#define HDIM 128
#define GS 8
#define CH 1024                 // steps per chunk
#define NC (T_STEPS / CH)       // 32 chunks
#define NGRP (CH / GS)          // groups per chunk

typedef __attribute__((ext_vector_type(2))) float f32x2;
typedef __attribute__((ext_vector_type(4))) float f32x4;

__device__ __forceinline__ f32x2 lo2(f32x4 v) { return __builtin_shufflevector(v, v, 0, 1); }
__device__ __forceinline__ f32x2 hi2(f32x4 v) { return __builtin_shufflevector(v, v, 2, 3); }
__device__ __forceinline__ void pkfma(f32x2& acc, f32x2 a, f32x2 b) {
  asm("v_pk_fma_f32 %0, %1, %2, %0" : "+v"(acc) : "v"(a), "v"(b));
}
__device__ __forceinline__ float sigm(float x) {
  return __fdividef(1.f, 1.f + __expf(-x));
}
__device__ __forceinline__ float tanh_fast(float x) {
  x = fminf(15.f, fmaxf(-15.f, x));
  float e = __expf(2.f * x);
  return (e - 1.f) * __fdividef(1.f, e + 1.f);
}
// quad butterfly (xor1 then xor2 via DPP quad_perm) — all 4 lanes get the sum.
// Numerically identical to shfl_xor(1);shfl_xor(2); proven r6 (absmax 0.0).
__device__ __forceinline__ float red4q(float v) {
  int t = __builtin_amdgcn_mov_dpp(__builtin_bit_cast(int, v), 0xB1, 0xF, 0xF, true);
  v += __builtin_bit_cast(float, t);
  t = __builtin_amdgcn_mov_dpp(__builtin_bit_cast(int, v), 0x4E, 0xF, 0xF, true);
  v += __builtin_bit_cast(float, t);
  return v;
}
// Pinned loads: asm results cannot be rematerialized.
__device__ __forceinline__ f32x4 ld4_pin(const float* p) {
  f32x4 v;
  asm volatile("global_load_dwordx4 %0, %1, off" : "=v"(v) : "v"(p));
  return v;
}
__device__ __forceinline__ f32x2 ld2_pin(const float* p) {
  f32x2 v;
  asm volatile("global_load_dwordx2 %0, %1, off" : "=v"(v) : "v"(p));
  return v;
}
__device__ __forceinline__ float ld1_pin(const float* p) {
  float v;
  asm volatile("global_load_dword %0, %1, off" : "=v"(v) : "v"(p));
  return v;
}
__device__ __forceinline__ void vwait() {
  asm volatile("s_waitcnt vmcnt(0)" ::: "memory");
}

// Thread t: q=t&3 (32-col chunk), u=t>>2 (hidden unit; rows u,u+128,u+256).
// Weights PRE-ROTATED: slot r holds quad k=r^2q -> LDS h-reads are 16-way
// broadcast x 4 disjoint bank-quads (conflict-free, r2/r6-proven, PMC=0).
__device__ __forceinline__ void load_w3_pin(const float* __restrict__ W, int u, int q,
                                            f32x4 (&w0)[8], f32x4 (&w1)[8], f32x4 (&w2)[8]) {
  #pragma unroll
  for (int r = 0; r < 8; ++r) {
    const int k = r ^ (q << 1);
    const int col = 32 * q + 4 * k;
    w0[r] = ld4_pin(W + (size_t)u * 128 + col);
    w1[r] = ld4_pin(W + (size_t)(u + 128) * 128 + col);
    w2[r] = ld4_pin(W + (size_t)(u + 256) * 128 + col);
  }
}

// h-part of the 3 dots (48 pkfma), accumulating into c0,c1,c2 (no reduce here)
__device__ __forceinline__ void dot3_acc(const f32x4 (&w0)[8], const f32x4 (&w1)[8],
                                         const f32x4 (&w2)[8], const float* hb, int q,
                                         f32x2& c0, f32x2& c1, f32x2& c2) {
  const int base = 32 * q;
  #pragma unroll
  for (int r = 0; r < 8; ++r) {
    const int k = r ^ (q << 1);
    f32x4 h4 = *(const f32x4*)(hb + base + 4 * k);
    f32x2 hl = lo2(h4), hh = hi2(h4);
    pkfma(c0, lo2(w0[r]), hl); pkfma(c0, hi2(w0[r]), hh);
    pkfma(c1, lo2(w1[r]), hl); pkfma(c1, hi2(w1[r]), hh);
    pkfma(c2, lo2(w2[r]), hl); pkfma(c2, hi2(w2[r]), hh);
  }
}

// ===================== block 0: layer-0 recurrence (chunk c) =====================
__device__ __noinline__ void role_l0(const float* __restrict__ x,
                                     const float* __restrict__ w_ih0,
                                     const float* __restrict__ w_hh0,
                                     const float* __restrict__ b_ih0,
                                     const float* __restrict__ b_hh0,
                                     float* __restrict__ h0, int c) {
  __shared__ __align__(16) float hbuf[2][HDIM];
  const int tid = threadIdx.x, q = tid & 3, u = tid >> 2;
  f32x4 w0[8], w1[8], w2[8];
  load_w3_pin(w_hh0, u, q, w0, w1, w2);
  // lane q handles x cols {2q,2q+1}; butterfly sums the x-slices across lanes
  f32x2 wx0 = ld2_pin(w_ih0 + (size_t)u * 8 + 2 * q);
  f32x2 wx1 = ld2_pin(w_ih0 + (size_t)(u + 128) * 8 + 2 * q);
  f32x2 wx2 = ld2_pin(w_ih0 + (size_t)(u + 256) * 8 + 2 * q);
  const float bi_r = ld1_pin(b_ih0 + u), bh_r = ld1_pin(b_hh0 + u);
  const float bi_z = ld1_pin(b_ih0 + u + 128), bh_z = ld1_pin(b_hh0 + u + 128);
  const float bi_n = ld1_pin(b_ih0 + u + 256), bh_n = ld1_pin(b_hh0 + u + 256);
  vwait();
  const float bsr = bi_r + bh_r, bsz = bi_z + bh_z, bin = bi_n, bhn = bh_n;

  float hp = (c == 0) ? 0.f : h0[((size_t)c * CH - 1) * HDIM + u];
  if (q == 0) hbuf[0][u] = hp;
  const int t0 = c * CH;
  f32x2 xva = *(const f32x2*)(x + (size_t)t0 * 8 + 2 * q);
  f32x2 xvb = *(const f32x2*)(x + (size_t)(t0 + 1) * 8 + 2 * q);
  __syncthreads();

  for (int s2 = 0; s2 < CH / 2; ++s2) {
    const int t = t0 + 2 * s2;
    const int tp2 = (t + 2 < T_STEPS) ? t + 2 : T_STEPS - 1;  // clamped prefetch
    const int tp3 = (t + 3 < T_STEPS) ? t + 3 : T_STEPS - 1;
    f32x2 xn0 = *(const f32x2*)(x + (size_t)tp2 * 8 + 2 * q);
    f32x2 xn1 = *(const f32x2*)(x + (size_t)tp3 * 8 + 2 * q);
    #pragma unroll
    for (int pr = 0; pr < 2; ++pr) {   // two steps: parity 0 then 1
      f32x2 c0 = {0.f, 0.f}, c1 = {0.f, 0.f}, c2 = {0.f, 0.f}, c3 = {0.f, 0.f};
      const f32x2 xv = pr ? xvb : xva;
      pkfma(c0, wx0, xv);              // r-gate x-part (merged with h-part)
      pkfma(c1, wx1, xv);              // z-gate x-part
      pkfma(c3, wx2, xv);              // n-gate x-part (SEPARATE: r scales h-part only)
      dot3_acc(w0, w1, w2, hbuf[pr], q, c0, c1, c2);
      const float a0 = red4q(c0.x + c0.y);
      const float a1 = red4q(c1.x + c1.y);
      const float a2 = red4q(c2.x + c2.y);
      const float a3 = red4q(c3.x + c3.y);
      const float rr = sigm(a0 + bsr);
      const float zz = sigm(a1 + bsz);
      const float nn = tanh_fast((a3 + bin) + rr * (a2 + bhn));
      hp = (1.f - zz) * nn + zz * hp;  // all 4 lanes identical
      if (q == 0) {
        hbuf[pr ^ 1][u] = hp;
        h0[(size_t)(t + pr) * HDIM + u] = hp;
      }
      __syncthreads();
    }
    xva = xn0; xvb = xn1;
  }
}

// ===================== block 1: layer-1 recurrence (chunk c) =====================
__device__ __noinline__ void role_l1(const float* __restrict__ w_hh1,
                                     const float* __restrict__ b_hh1,
                                     const float* __restrict__ gi1s,  // ring slot base
                                     float* __restrict__ hstate1,
                                     float* __restrict__ out, int c) {
  __shared__ __align__(16) float hbuf[2][HDIM];
  __shared__ __align__(16) float sg[2][GS * 512];   // 2 x 16 KB gi1 staging
  const int tid = threadIdx.x, q = tid & 3, u = tid >> 2;
  f32x4 w0[8], w1[8], w2[8];
  load_w3_pin(w_hh1, u, q, w0, w1, w2);
  const float bhr_ = ld1_pin(b_hh1 + u);
  const float bhz_ = ld1_pin(b_hh1 + u + 128);
  const float bhn_ = ld1_pin(b_hh1 + u + 256);
  vwait();
  const float bhr = bhr_, bhz = bhz_, bhn = bhn_;

  float hp = (c == 0) ? 0.f : hstate1[u];
  if (q == 0) hbuf[0][u] = hp;
  // blocking preload of group 0 (16 KB)
  ((f32x4*)sg[0])[tid] = ((const f32x4*)gi1s)[tid];
  ((f32x4*)sg[0])[tid + 512] = ((const f32x4*)gi1s)[tid + 512];
  __syncthreads();

  int cur = 0;
  for (int g = 0; g < NGRP; ++g) {
    f32x4 pf0, pf1;
    const bool hpf = (g + 1 < NGRP);
    if (hpf) {  // issue next group's loads early; LDS-write at s==GS-2
      const f32x4* b4 = (const f32x4*)(gi1s + (size_t)(g + 1) * GS * 512);
      pf0 = b4[tid]; pf1 = b4[tid + 512];
    }
    #pragma unroll
    for (int s = 0; s < GS; ++s) {
      const int pr = s & 1;
      f32x2 c0 = {0.f, 0.f}, c1 = {0.f, 0.f}, c2 = {0.f, 0.f};
      dot3_acc(w0, w1, w2, hbuf[pr], q, c0, c1, c2);
      const float a0 = red4q(c0.x + c0.y);
      const float a1 = red4q(c1.x + c1.y);
      const float a2 = red4q(c2.x + c2.y);
      const f32x4 gv = *(const f32x4*)&sg[cur][s * 512 + 4 * u];  // broadcast read
      if (s == GS - 2 && hpf) {
        ((f32x4*)sg[cur ^ 1])[tid] = pf0;
        ((f32x4*)sg[cur ^ 1])[tid + 512] = pf1;
      }
      const float rr = sigm(gv.x + a0 + bhr);
      const float zz = sigm(gv.y + a1 + bhz);
      const float nn = tanh_fast(gv.z + rr * (a2 + bhn));
      hp = (1.f - zz) * nn + zz * hp;
      if (q == 0) hbuf[pr ^ 1][u] = hp;
      __syncthreads();
    }
    cur ^= 1;
  }
  if (q == 0) { hstate1[u] = hp; out[u] = hp; }
}

// ========== blocks 2..4: gi1[t] = w_ih1 @ h0[t] + b_ih1 (one gate block each) ==========
__device__ __noinline__ void role_army(const float* __restrict__ h0c,
                                       const float* __restrict__ w_ih1,
                                       const float* __restrict__ b_ih1,
                                       float* __restrict__ gi1s, int rb) {
  __shared__ __align__(16) float hsg[2][GS * HDIM];  // 2 x 4 KB h0 staging
  const int tid = threadIdx.x, q = tid & 3, u = tid >> 2;
  const int row = rb * HDIM + u;
  f32x4 w[8];
  #pragma unroll
  for (int r = 0; r < 8; ++r)
    w[r] = ld4_pin(w_ih1 + (size_t)row * 128 + 32 * q + 4 * (r ^ (q << 1)));
  const float bias_ = ld1_pin(b_ih1 + row);
  vwait();
  const float bias = bias_;

  if (tid < 256) ((f32x4*)hsg[0])[tid] = ((const f32x4*)h0c)[tid];
  __syncthreads();

  int cur = 0;
  for (int g = 0; g < NGRP; ++g) {
    f32x4 pf;
    const bool hpf = (g + 1 < NGRP) && (tid < 256);
    if (hpf) pf = ((const f32x4*)(h0c + (size_t)(g + 1) * GS * HDIM))[tid];
    #pragma unroll
    for (int s = 0; s < GS; ++s) {
      f32x2 cc = {0.f, 0.f};
      const float* hb = hsg[cur] + s * HDIM + 32 * q;
      #pragma unroll
      for (int r = 0; r < 8; ++r) {
        f32x4 h4 = *(const f32x4*)(hb + 4 * (r ^ (q << 1)));
        pkfma(cc, lo2(w[r]), lo2(h4));
        pkfma(cc, hi2(w[r]), hi2(h4));
      }
      const float a = red4q(cc.x + cc.y);
      if (q == 0) gi1s[(size_t)(g * GS + s) * 512 + 4 * u + rb] = a + bias;
    }
    if (hpf) ((f32x4*)hsg[cur ^ 1])[tid] = pf;
    __syncthreads();  // one barrier per group: guards hsg swap
    cur ^= 1;
  }
}

__global__ __launch_bounds__(512, 2)
void gru_pipe(const float* __restrict__ x,
              const float* __restrict__ w_ih0, const float* __restrict__ w_hh0,
              const float* __restrict__ b_ih0, const float* __restrict__ b_hh0,
              const float* __restrict__ w_ih1, const float* __restrict__ w_hh1,
              const float* __restrict__ b_ih1, const float* __restrict__ b_hh1,
              float* __restrict__ out, float* __restrict__ h0,
              float* __restrict__ gi1_ring, float* __restrict__ hstate1, int k) {
  const int bid = blockIdx.x;
  if (bid == 0) {
    if (k < NC)
      role_l0(x, w_ih0, w_hh0, b_ih0, b_hh0, h0, k);
  } else if (bid == 1) {
    if (k >= 2)
      role_l1(w_hh1, b_hh1, gi1_ring + (size_t)((k - 2) & 1) * CH * 512,
              hstate1, out, k - 2);
  } else {
    const int c = k - 1;
    if (c >= 0 && c < NC)
      role_army(h0 + (size_t)c * CH * HDIM, w_ih1, b_ih1,
                gi1_ring + (size_t)(c & 1) * CH * 512, bid - 2);
  }
}

extern "C" void kernel_launch(void* const* d_in, const int* in_sizes, int n_in,
                              void* d_out, int out_size, void* d_ws, size_t ws_size,
                              hipStream_t stream) {
  (void)in_sizes; (void)n_in; (void)out_size; (void)ws_size;
  const float* x     = (const float*)d_in[0];
  const float* w_ih0 = (const float*)d_in[1];
  const float* w_hh0 = (const float*)d_in[2];
  const float* b_ih0 = (const float*)d_in[3];
  const float* b_hh0 = (const float*)d_in[4];
  const float* w_ih1 = (const float*)d_in[5];
  const float* w_hh1 = (const float*)d_in[6];
  const float* b_ih1 = (const float*)d_in[7];
  const float* b_hh1 = (const float*)d_in[8];
  float* out = (float*)d_out;

  // ws: h0 full sequence (16 MB) | gi1 2-chunk ring (4 MB) | hstate1 (512 B)
  float* h0       = (float*)d_ws;
  float* gi1_ring = h0 + (size_t)T_STEPS * HDIM;
  float* hstate1  = gi1_ring + (size_t)2 * CH * 512;

  for (int k = 0; k <= NC + 1; ++k) {
    hipLaunchKernelGGL(gru_pipe, dim3(5), dim3(512), 0, stream,
                       x, w_ih0, w_hh0, b_ih0, b_hh0,
                       w_ih1, w_hh1, b_ih1, b_hh1, out,
                       h0, gi1_ring, hstate1, k);
  }
}